// Round 7
// baseline (65.942 us; speedup 1.0000x reference)
//
#include <hip/hip_runtime.h>

typedef __attribute__((ext_vector_type(8))) short bf16x8;
typedef __attribute__((ext_vector_type(4))) float f32x4;
typedef unsigned int u32;
typedef unsigned short u16;

#define BB 8192
#define DD 128
#define CC 64
#define NSLICE 16
#define SLICE_COLS 512       // 8192/16
#define NTILES 8             // 512/64
#define NBIN 64
#define BINSTRIDE 16         // floats; 64B -> one bin per L2 line
#define NFBLK (BB / 4)       // k_finalize block count

typedef __attribute__((address_space(1))) void gvoid;
typedef __attribute__((address_space(3))) void lvoid;

static __device__ __forceinline__ u16 f2bf(float x) {
    u32 u = __float_as_uint(x);
    return (u16)((u + 0x7FFFu + ((u >> 16) & 1u)) >> 16);
}
static __device__ __forceinline__ u32 umaxu(u32 a, u32 b) { return a > b ? a : b; }
static __device__ __forceinline__ u32 uminu(u32 a, u32 b) { return a < b ? a : b; }

// (val & mask) | (idx & ~mask) in one VALU op; mask uniform -> SGPR
// NOTE: v_pk_fma_f32 via raw asm was tried and mis-encoded half-selects
// (absmax 0.78) -- packed VOP3P is banned here without disasm verification.
static __device__ __forceinline__ u32 bfi_key(u32 mask, u32 val, u32 idx) {
    u32 r;
    asm("v_bfi_b32 %0, %1, %2, %3" : "=v"(r) : "s"(mask), "v"(val), "v"(idx));
    return r;
}

// direct global->LDS DMA, 16B per lane; dest is wave-uniform base + lane*16
static __device__ __forceinline__ void gload16(const void* g, void* l) {
    __builtin_amdgcn_global_load_lds((const gvoid*)g, (lvoid*)l, 16, 0, 0);
}

// ---------------- kernel 0: row squared norms + bf16 convert + key/bin init ----------------
__global__ __launch_bounds__(256) void k_prep(const float* __restrict__ E,
                                              float* __restrict__ sq,
                                              u16* __restrict__ Ebf,
                                              u32* __restrict__ gmax,
                                              u32* __restrict__ gmin,
                                              float* __restrict__ bins,
                                              u32* __restrict__ cnt) {
    // init this block's 4 rows' global key cells (kernel boundary orders vs k_mine)
    if (threadIdx.x < 4) {
        int r = blockIdx.x * 4 + threadIdx.x;
        gmax[r] = 0u;
        gmin[r] = 0xFFFFFFFFu;
    }
    if (blockIdx.x == 0) {
        if (threadIdx.x < 2 * NBIN)
            bins[(threadIdx.x & (NBIN - 1)) * BINSTRIDE +
                 (threadIdx.x >= NBIN ? NBIN * BINSTRIDE : 0)] = 0.0f;
        if (threadIdx.x == 0) cnt[0] = 0u;
    }

    int row = blockIdx.x * 4 + (threadIdx.x >> 6);
    int l   = threadIdx.x & 63;
    float2 v = *reinterpret_cast<const float2*>(E + (size_t)row * DD + l * 2);
    ushort2 bv = make_ushort2(f2bf(v.x), f2bf(v.y));
    *reinterpret_cast<ushort2*>(Ebf + (size_t)row * DD + l * 2) = bv;
    float s = v.x * v.x + v.y * v.y;
    #pragma unroll
    for (int m = 32; m; m >>= 1) s += __shfl_xor(s, m);
    if (l == 0) sq[row] = s;
}

// ---------------- kernel 1: bf16 MFMA pairwise + packed-key batch-hard mining ----------------
// Grid: (32, 16). Block: 256 thr = 4 waves; wave w owns rows rowW..rowW+63.
// Slice = 512 cols = 8 tiles of 64. 3-deep global_load_lds ring
// (pre-swizzled source, linear LDS dest), counted vmcnt(4), ONE barrier per tile.
// Slice results combined via device-scope atomicMax/Min on packed keys
// (unique index low-bits -> final keys bit-identical to the partials path).
__global__ __launch_bounds__(256, 2) void k_mine(const u16* __restrict__ Ebf,
                                                 const float* __restrict__ sq,
                                                 const int* __restrict__ lab,
                                                 u32* __restrict__ gmax,
                                                 u32* __restrict__ gmin) {
    __shared__ uint4 Bt4[3][1024];               // 3 x 16 KB B tiles (ring)

    const int tid = threadIdx.x;
    const int l   = tid & 63;
    const int w   = tid >> 6;
    const int l15 = l & 15;
    const int l4  = l >> 4;
    const int rowW = blockIdx.x * 256 + w * 64;
    const int col0 = blockIdx.y * SLICE_COLS;

    // ---- A fragments in registers: a[rb][kk], lane holds row (rowW+rb*16+l15), k = kk*32 + l4*8 .. +8 ----
    bf16x8 a[4][4];
    #pragma unroll
    for (int rb = 0; rb < 4; ++rb)
        #pragma unroll
        for (int kk = 0; kk < 4; ++kk)
            a[rb][kk] = *reinterpret_cast<const bf16x8*>(
                Ebf + (size_t)(rowW + rb * 16 + l15) * DD + kk * 32 + l4 * 8);

    // row labels for this lane's 16 accumulator row-slots: row = rowW + rb*16 + l4*4 + e
    int labr[4][4];
    #pragma unroll
    for (int rb = 0; rb < 4; ++rb)
        #pragma unroll
        for (int e = 0; e < 4; ++e)
            labr[rb][e] = lab[rowW + rb * 16 + l4 * 4 + e];

    u32 kmax[4][4], kmin[4][4];
    #pragma unroll
    for (int rb = 0; rb < 4; ++rb)
        #pragma unroll
        for (int e = 0; e < 4; ++e) { kmax[rb][e] = 0u; kmin[rb][e] = 0xFFFFFFFFu; }

    // opaque zero C-operand: first MFMA of each chain reads Z instead of
    // zero-initing 16 acc regs per cb (kills 64 v_mov per tile per wave).
    // Verified bit-exact in rounds 3/5/6 benches.
    f32x4 Z = (f32x4){0.f, 0.f, 0.f, 0.f};
    asm volatile("" : "+v"(Z));

    // hoisted, tile-invariant swizzled LDS offsets for the b-fragment reads
    u32 boff[4][4];
    #pragma unroll
    for (int cb = 0; cb < 4; ++cb)
        #pragma unroll
        for (int kk = 0; kk < 4; ++kk) {
            int r = cb * 16 + l15;
            boff[cb][kk] = (u32)(r * 256 + ((kk * 64 + l4 * 16) ^ ((r & 7) << 4)));
        }

    // staging coords (constant across tiles)
    const int srow = tid >> 4;            // 0..15
    const int sx   = (tid & 15) * 16;     // 0..240

    // DMA stage of tile tt into ring slot bufi. LDS dest linear; global source
    // pre-swizzled so LDS[r*256 + c] = G[(colT+r)*256 + (c ^ swz(r))].
    auto stage = [&](int bufi, int tt) {
        const char* gs = (const char*)Ebf + (size_t)(col0 + tt * 64) * 256;
        char* lb = (char*)&Bt4[bufi][0] + w * 1024;   // wave-uniform base
        #pragma unroll
        for (int rd = 0; rd < 4; ++rd) {
            int r = rd * 16 + srow;
            gload16(gs + r * 256 + (sx ^ ((r & 7) << 4)), lb + rd * 4096);
        }
    };

    stage(0, 0);
    const u32 HM = 0xFFFFE000u;
    int cur = 0;

    for (int t = 0; t < NTILES; ++t) {
        int nxt = cur + 1; if (nxt == 3) nxt = 0;
        if (t + 1 < NTILES) {
            stage(nxt, t + 1);                               // 4 loads stay in flight
            asm volatile("s_waitcnt vmcnt(4)" ::: "memory"); // own stage(t) landed
        } else {
            asm volatile("s_waitcnt vmcnt(0)" ::: "memory");
        }
        __builtin_amdgcn_s_barrier();       // all waves' stage(t) landed; buf reuse safe
        asm volatile("" ::: "memory");      // keep ds_reads below the barrier

        const char* Bt = (const char*)&Bt4[cur][0];
        const int colT = col0 + t * 64;

        // column metadata for this lane: col = colT + cb*16 + l15
        float cbias[4]; int labc[4]; u32 jn[4];
        #pragma unroll
        for (int cb = 0; cb < 4; ++cb) {
            int gj = colT + cb * 16 + l15;
            cbias[cb] = sq[gj] + 1024.0f;    // bias keeps key value strictly positive
            labc[cb]  = lab[gj];
            jn[cb] = (u32)gj;
            // jx = 8191-gj = gj ^ 0x1FFF (all-ones subtrahend, no borrows)
        }

        const bool isdiag = (rowW == colT);

        auto tilebody = [&](bool dg) {
            #pragma unroll
            for (int cb = 0; cb < 4; ++cb) {
                // B fragments from swizzled LDS: lane row = cb*16+l15, k = kk*32 + l4*8
                bf16x8 b[4];
                #pragma unroll
                for (int kk = 0; kk < 4; ++kk)
                    b[kk] = *reinterpret_cast<const bf16x8*>(Bt + boff[cb][kk]);
                f32x4 acc[4];
                #pragma unroll
                for (int rb = 0; rb < 4; ++rb)
                    acc[rb] = __builtin_amdgcn_mfma_f32_16x16x32_bf16(
                        a[rb][0], b[0], Z, 0, 0, 0);
                #pragma unroll
                for (int kk = 1; kk < 4; ++kk)
                    #pragma unroll
                    for (int rb = 0; rb < 4; ++rb)
                        acc[rb] = __builtin_amdgcn_mfma_f32_16x16x32_bf16(
                            a[rb][kk], b[kk], acc[rb], 0, 0, 0);

                // mining epilogue: val = (sq_j + 1024) - 2*ip ; keyn = bfi(val, j);
                // keyx = keyn ^ 0x1FFF (== bfi(val, 8191-j), bit-exact)
                #pragma unroll
                for (int rb = 0; rb < 4; ++rb)
                    #pragma unroll
                    for (int e = 0; e < 4; ++e) {
                        float val = fmaf(acc[rb][e], -2.0f, cbias[cb]);
                        u32 vb = __float_as_uint(val);
                        u32 keyn = bfi_key(HM, vb, jn[cb]);
                        u32 keyx = keyn ^ 0x1FFFu;
                        bool eq = (labr[rb][e] == labc[cb]);
                        bool selfhit = dg && ((rb * 16 + l4 * 4 + e) == (cb * 16 + l15));
                        u32 cx = (eq && !selfhit) ? keyx : 0u;
                        u32 cn = eq ? 0xFFFFFFFFu : keyn;
                        kmax[rb][e] = umaxu(kmax[rb][e], cx);
                        kmin[rb][e] = uminu(kmin[rb][e], cn);
                    }
            }
        };
        if (isdiag) tilebody(true); else tilebody(false);

        cur = nxt;
    }

    // cross-lane reduce over the 16 l15 lanes of each l4 group, then device-scope
    // atomic combine into the single per-row key (identical winners: unique keys)
    #pragma unroll
    for (int rb = 0; rb < 4; ++rb)
        #pragma unroll
        for (int e = 0; e < 4; ++e) {
            u32 kx = kmax[rb][e], kn = kmin[rb][e];
            #pragma unroll
            for (int m = 1; m < 16; m <<= 1) {
                u32 ox = (u32)__shfl_xor((int)kx, m); kx = umaxu(kx, ox);
                u32 on = (u32)__shfl_xor((int)kn, m); kn = uminu(kn, on);
            }
            if (l15 == 0) {
                int row = rowW + rb * 16 + l4 * 4 + e;
                atomicMax(&gmax[row], kx);
                atomicMin(&gmin[row], kn);
            }
        }
}

// ---------------- kernel 2: exact fp32 loss + binned atomic reduce + last-block fold ----------------
// No fences anywhere (R3 lesson: __threadfence = per-block L2 writeback, catastrophic).
// Visibility chain: bin atomicAdds (device-scope) -> s_waitcnt vmcnt(0) (ack only)
// -> __syncthreads -> counter atomicAdd; last block reads bins via atomic RMW.
__global__ __launch_bounds__(256) void k_finalize(const float* __restrict__ E,
                                                  const float* __restrict__ M,
                                                  const int* __restrict__ lab,
                                                  const u32* __restrict__ gmax,
                                                  const u32* __restrict__ gmin,
                                                  float* __restrict__ bins,
                                                  u32* __restrict__ cnt,
                                                  float* __restrict__ out) {
    __shared__ int islast;

    int row = blockIdx.x * 4 + (threadIdx.x >> 6);
    int l   = threadIdx.x & 63;

    u32 kx = gmax[row];          // final keys (written by k_mine, kernel boundary)
    u32 kn = gmin[row];
    bool valid = (kx != 0u) && (kn != 0xFFFFFFFFu);
    int hp = 8191 - (int)(kx & 0x1FFFu);
    int hn = (int)(kn & 0x1FFFu);

    float2 ei = *reinterpret_cast<const float2*>(E + (size_t)row * DD + l * 2);
    float2 ep = *reinterpret_cast<const float2*>(E + (size_t)hp  * DD + l * 2);
    float2 en = *reinterpret_cast<const float2*>(E + (size_t)hn  * DD + l * 2);
    float dx = ei.x - ep.x, dy = ei.y - ep.y;
    float sap = dx * dx + dy * dy;
    dx = ei.x - en.x; dy = ei.y - en.y;
    float san = dx * dx + dy * dy;
    #pragma unroll
    for (int m = 32; m; m >>= 1) {
        sap += __shfl_xor(sap, m);
        san += __shfl_xor(san, m);
    }
    if (l == 0) {
        float dap = sqrtf(sap), dan = sqrtf(san);
        float mg = M[lab[row] * CC + lab[hn]];
        float lo = fmaxf(dap - dan + mg, 0.0f);
        int bin = row & (NBIN - 1);
        atomicAdd(&bins[bin * BINSTRIDE], valid ? lo : 0.0f);
        atomicAdd(&bins[NBIN * BINSTRIDE + bin * BINSTRIDE], valid ? 1.0f : 0.0f);
    }

    // per-wave: wait for own atomics to retire at the coherence point (no cache flush)
    asm volatile("s_waitcnt vmcnt(0)" ::: "memory");
    __syncthreads();
    if (threadIdx.x == 0) {
        u32 old = atomicAdd(cnt, 1u);
        islast = (old == (u32)(NFBLK - 1));
    }
    __syncthreads();
    if (islast && threadIdx.x < 64) {
        int t = threadIdx.x;
        // atomic RMW reads: coherent view of all completed bin adds
        float a = atomicAdd(&bins[t * BINSTRIDE], 0.0f);
        float b = atomicAdd(&bins[NBIN * BINSTRIDE + t * BINSTRIDE], 0.0f);
        #pragma unroll
        for (int m = 32; m; m >>= 1) {
            a += __shfl_xor(a, m);
            b += __shfl_xor(b, m);
        }
        if (t == 0) out[0] = a / fmaxf(b, 1.0f);
    }
}

extern "C" void kernel_launch(void* const* d_in, const int* in_sizes, int n_in,
                              void* d_out, int out_size, void* d_ws, size_t ws_size,
                              hipStream_t stream) {
    const float* E   = (const float*)d_in[0];   // [B][D] fp32
    const float* M   = (const float*)d_in[1];   // [C][C] fp32
    const int*   lab = (const int*)d_in[2];     // [B]
    float* out = (float*)d_out;

    char* ws = (char*)d_ws;
    u16*   Ebf  = (u16*)ws;        ws += (size_t)BB * DD * 2;     // 2 MB
    float* sq   = (float*)ws;      ws += (size_t)BB * 4;
    u32*   gmax = (u32*)ws;        ws += (size_t)BB * 4;          // 32 KB
    u32*   gmin = (u32*)ws;        ws += (size_t)BB * 4;          // 32 KB
    float* bins = (float*)ws;      ws += (size_t)2 * NBIN * BINSTRIDE * 4; // 8 KB
    u32*   cnt  = (u32*)ws;        ws += 64;

    k_prep<<<BB / 4, 256, 0, stream>>>(E, sq, Ebf, gmax, gmin, bins, cnt);
    k_mine<<<dim3(BB / 256, NSLICE), 256, 0, stream>>>(Ebf, sq, lab, gmax, gmin);
    k_finalize<<<BB / 4, 256, 0, stream>>>(E, M, lab, gmax, gmin, bins, cnt, out);
}

// Round 8
// 46.373 us; speedup vs baseline: 1.4220x; 1.4220x over previous
//
#include <hip/hip_runtime.h>

typedef __attribute__((ext_vector_type(8))) short bf16x8;
typedef __attribute__((ext_vector_type(4))) float f32x4;
typedef unsigned int u32;
typedef unsigned short u16;

#define BB 8192
#define DD 128
#define CC 64
#define NSLICE 16
#define SLICE_COLS 512       // 8192/16
#define NTILES 8             // 512/64
#define NBIN 64
#define BINSTRIDE 16         // floats; 64B -> one bin per L2 line

typedef __attribute__((address_space(1))) void gvoid;
typedef __attribute__((address_space(3))) void lvoid;

static __device__ __forceinline__ u16 f2bf(float x) {
    u32 u = __float_as_uint(x);
    return (u16)((u + 0x7FFFu + ((u >> 16) & 1u)) >> 16);
}
static __device__ __forceinline__ u32 umaxu(u32 a, u32 b) { return a > b ? a : b; }
static __device__ __forceinline__ u32 uminu(u32 a, u32 b) { return a < b ? a : b; }

// (val & mask) | (idx & ~mask) in one VALU op; mask uniform -> SGPR
// NOTE: v_pk_fma_f32 via raw asm mis-encoded half-selects (absmax 0.78) - banned.
// NOTE: single-address grid-wide atomic counters serialize ~10ns/op at the
// coherence point (~20us for 2048 blocks) - banned (R3, R7 regressions).
static __device__ __forceinline__ u32 bfi_key(u32 mask, u32 val, u32 idx) {
    u32 r;
    asm("v_bfi_b32 %0, %1, %2, %3" : "=v"(r) : "s"(mask), "v"(val), "v"(idx));
    return r;
}

// direct global->LDS DMA, 16B per lane; dest is wave-uniform base + lane*16
static __device__ __forceinline__ void gload16(const void* g, void* l) {
    __builtin_amdgcn_global_load_lds((const gvoid*)g, (lvoid*)l, 16, 0, 0);
}

// ---------------- kernel 0: row squared norms + bf16 convert + key/bin init ----------------
__global__ __launch_bounds__(256) void k_prep(const float* __restrict__ E,
                                              float* __restrict__ sq,
                                              u16* __restrict__ Ebf,
                                              u32* __restrict__ gmax,
                                              u32* __restrict__ gmin,
                                              float* __restrict__ bins) {
    // init this block's 4 rows' global key cells (kernel boundary orders vs k_mine)
    if (threadIdx.x < 4) {
        int r = blockIdx.x * 4 + threadIdx.x;
        gmax[r] = 0u;
        gmin[r] = 0xFFFFFFFFu;
    }
    if (blockIdx.x == 0 && threadIdx.x < 2 * NBIN)
        bins[(threadIdx.x & (NBIN - 1)) * BINSTRIDE +
             (threadIdx.x >= NBIN ? NBIN * BINSTRIDE : 0)] = 0.0f;

    int row = blockIdx.x * 4 + (threadIdx.x >> 6);
    int l   = threadIdx.x & 63;
    float2 v = *reinterpret_cast<const float2*>(E + (size_t)row * DD + l * 2);
    ushort2 bv = make_ushort2(f2bf(v.x), f2bf(v.y));
    *reinterpret_cast<ushort2*>(Ebf + (size_t)row * DD + l * 2) = bv;
    float s = v.x * v.x + v.y * v.y;
    #pragma unroll
    for (int m = 32; m; m >>= 1) s += __shfl_xor(s, m);
    if (l == 0) sq[row] = s;
}

// ---------------- kernel 1: bf16 MFMA pairwise + packed-key batch-hard mining ----------------
// Grid: (32, 16). Block: 256 thr = 4 waves; wave w owns rows rowW..rowW+63.
// Slice = 512 cols = 8 tiles of 64. 3-deep global_load_lds ring
// (pre-swizzled source, linear LDS dest), counted vmcnt(4), ONE barrier per tile.
// Slice results combined via device-scope atomicMax/Min on packed keys:
// 8192 distinct addresses, 16-way contention each (channel-parallel, NOT the
// single-hot-address pattern). Final keys bit-identical to the partials path.
__global__ __launch_bounds__(256, 2) void k_mine(const u16* __restrict__ Ebf,
                                                 const float* __restrict__ sq,
                                                 const int* __restrict__ lab,
                                                 u32* __restrict__ gmax,
                                                 u32* __restrict__ gmin) {
    __shared__ uint4 Bt4[3][1024];               // 3 x 16 KB B tiles (ring)

    const int tid = threadIdx.x;
    const int l   = tid & 63;
    const int w   = tid >> 6;
    const int l15 = l & 15;
    const int l4  = l >> 4;
    const int rowW = blockIdx.x * 256 + w * 64;
    const int col0 = blockIdx.y * SLICE_COLS;

    // ---- A fragments in registers: a[rb][kk], lane holds row (rowW+rb*16+l15), k = kk*32 + l4*8 .. +8 ----
    bf16x8 a[4][4];
    #pragma unroll
    for (int rb = 0; rb < 4; ++rb)
        #pragma unroll
        for (int kk = 0; kk < 4; ++kk)
            a[rb][kk] = *reinterpret_cast<const bf16x8*>(
                Ebf + (size_t)(rowW + rb * 16 + l15) * DD + kk * 32 + l4 * 8);

    // row labels for this lane's 16 accumulator row-slots: row = rowW + rb*16 + l4*4 + e
    int labr[4][4];
    #pragma unroll
    for (int rb = 0; rb < 4; ++rb)
        #pragma unroll
        for (int e = 0; e < 4; ++e)
            labr[rb][e] = lab[rowW + rb * 16 + l4 * 4 + e];

    u32 kmax[4][4], kmin[4][4];
    #pragma unroll
    for (int rb = 0; rb < 4; ++rb)
        #pragma unroll
        for (int e = 0; e < 4; ++e) { kmax[rb][e] = 0u; kmin[rb][e] = 0xFFFFFFFFu; }

    // opaque zero C-operand: first MFMA of each chain reads Z instead of
    // zero-initing 16 acc regs per cb (kills 64 v_mov per tile per wave).
    f32x4 Z = (f32x4){0.f, 0.f, 0.f, 0.f};
    asm volatile("" : "+v"(Z));

    // hoisted, tile-invariant swizzled LDS offsets for the b-fragment reads
    u32 boff[4][4];
    #pragma unroll
    for (int cb = 0; cb < 4; ++cb)
        #pragma unroll
        for (int kk = 0; kk < 4; ++kk) {
            int r = cb * 16 + l15;
            boff[cb][kk] = (u32)(r * 256 + ((kk * 64 + l4 * 16) ^ ((r & 7) << 4)));
        }

    // staging coords (constant across tiles)
    const int srow = tid >> 4;            // 0..15
    const int sx   = (tid & 15) * 16;     // 0..240

    // DMA stage of tile tt into ring slot bufi. LDS dest linear; global source
    // pre-swizzled so LDS[r*256 + c] = G[(colT+r)*256 + (c ^ swz(r))].
    auto stage = [&](int bufi, int tt) {
        const char* gs = (const char*)Ebf + (size_t)(col0 + tt * 64) * 256;
        char* lb = (char*)&Bt4[bufi][0] + w * 1024;   // wave-uniform base
        #pragma unroll
        for (int rd = 0; rd < 4; ++rd) {
            int r = rd * 16 + srow;
            gload16(gs + r * 256 + (sx ^ ((r & 7) << 4)), lb + rd * 4096);
        }
    };

    stage(0, 0);
    const u32 HM = 0xFFFFE000u;
    int cur = 0;

    for (int t = 0; t < NTILES; ++t) {
        int nxt = cur + 1; if (nxt == 3) nxt = 0;
        if (t + 1 < NTILES) {
            stage(nxt, t + 1);                               // 4 loads stay in flight
            asm volatile("s_waitcnt vmcnt(4)" ::: "memory"); // own stage(t) landed
        } else {
            asm volatile("s_waitcnt vmcnt(0)" ::: "memory");
        }
        __builtin_amdgcn_s_barrier();       // all waves' stage(t) landed; buf reuse safe
        asm volatile("" ::: "memory");      // keep ds_reads below the barrier

        const char* Bt = (const char*)&Bt4[cur][0];
        const int colT = col0 + t * 64;

        // column metadata for this lane: col = colT + cb*16 + l15
        float cbias[4]; int labc[4]; u32 jn[4];
        #pragma unroll
        for (int cb = 0; cb < 4; ++cb) {
            int gj = colT + cb * 16 + l15;
            cbias[cb] = sq[gj] + 1024.0f;    // bias keeps key value strictly positive
            labc[cb]  = lab[gj];
            jn[cb] = (u32)gj;
            // jx = 8191-gj = gj ^ 0x1FFF (all-ones subtrahend, no borrows)
        }

        const bool isdiag = (rowW == colT);

        auto tilebody = [&](bool dg) {
            #pragma unroll
            for (int cb = 0; cb < 4; ++cb) {
                // B fragments from swizzled LDS: lane row = cb*16+l15, k = kk*32 + l4*8
                bf16x8 b[4];
                #pragma unroll
                for (int kk = 0; kk < 4; ++kk)
                    b[kk] = *reinterpret_cast<const bf16x8*>(Bt + boff[cb][kk]);
                f32x4 acc[4];
                #pragma unroll
                for (int rb = 0; rb < 4; ++rb)
                    acc[rb] = __builtin_amdgcn_mfma_f32_16x16x32_bf16(
                        a[rb][0], b[0], Z, 0, 0, 0);
                #pragma unroll
                for (int kk = 1; kk < 4; ++kk)
                    #pragma unroll
                    for (int rb = 0; rb < 4; ++rb)
                        acc[rb] = __builtin_amdgcn_mfma_f32_16x16x32_bf16(
                            a[rb][kk], b[kk], acc[rb], 0, 0, 0);

                // mining epilogue: val = (sq_j + 1024) - 2*ip ; keyn = bfi(val, j);
                // keyx = keyn ^ 0x1FFF (== bfi(val, 8191-j), bit-exact)
                #pragma unroll
                for (int rb = 0; rb < 4; ++rb)
                    #pragma unroll
                    for (int e = 0; e < 4; ++e) {
                        float val = fmaf(acc[rb][e], -2.0f, cbias[cb]);
                        u32 vb = __float_as_uint(val);
                        u32 keyn = bfi_key(HM, vb, jn[cb]);
                        u32 keyx = keyn ^ 0x1FFFu;
                        bool eq = (labr[rb][e] == labc[cb]);
                        bool selfhit = dg && ((rb * 16 + l4 * 4 + e) == (cb * 16 + l15));
                        u32 cx = (eq && !selfhit) ? keyx : 0u;
                        u32 cn = eq ? 0xFFFFFFFFu : keyn;
                        kmax[rb][e] = umaxu(kmax[rb][e], cx);
                        kmin[rb][e] = uminu(kmin[rb][e], cn);
                    }
            }
        };
        if (isdiag) tilebody(true); else tilebody(false);

        cur = nxt;
    }

    // cross-lane reduce over the 16 l15 lanes of each l4 group, then device-scope
    // atomic combine into the single per-row key (identical winners: unique keys)
    #pragma unroll
    for (int rb = 0; rb < 4; ++rb)
        #pragma unroll
        for (int e = 0; e < 4; ++e) {
            u32 kx = kmax[rb][e], kn = kmin[rb][e];
            #pragma unroll
            for (int m = 1; m < 16; m <<= 1) {
                u32 ox = (u32)__shfl_xor((int)kx, m); kx = umaxu(kx, ox);
                u32 on = (u32)__shfl_xor((int)kn, m); kn = uminu(kn, on);
            }
            if (l15 == 0) {
                int row = rowW + rb * 16 + l4 * 4 + e;
                atomicMax(&gmax[row], kx);
                atomicMin(&gmin[row], kn);
            }
        }
}

// ---------------- kernel 2: exact fp32 loss + binned atomic reduce ----------------
// Keys read directly (kernel boundary after k_mine). Binned atomics only
// (64 padded addresses) - the verified-fast pattern from round 6.
__global__ __launch_bounds__(256) void k_finalize(const float* __restrict__ E,
                                                  const float* __restrict__ M,
                                                  const int* __restrict__ lab,
                                                  const u32* __restrict__ gmax,
                                                  const u32* __restrict__ gmin,
                                                  float* __restrict__ bins) {
    int row = blockIdx.x * 4 + (threadIdx.x >> 6);
    int l   = threadIdx.x & 63;

    u32 kx = gmax[row];
    u32 kn = gmin[row];
    bool valid = (kx != 0u) && (kn != 0xFFFFFFFFu);
    int hp = 8191 - (int)(kx & 0x1FFFu);
    int hn = (int)(kn & 0x1FFFu);

    float2 ei = *reinterpret_cast<const float2*>(E + (size_t)row * DD + l * 2);
    float2 ep = *reinterpret_cast<const float2*>(E + (size_t)hp  * DD + l * 2);
    float2 en = *reinterpret_cast<const float2*>(E + (size_t)hn  * DD + l * 2);
    float dx = ei.x - ep.x, dy = ei.y - ep.y;
    float sap = dx * dx + dy * dy;
    dx = ei.x - en.x; dy = ei.y - en.y;
    float san = dx * dx + dy * dy;
    #pragma unroll
    for (int m = 32; m; m >>= 1) {
        sap += __shfl_xor(sap, m);
        san += __shfl_xor(san, m);
    }
    if (l == 0) {
        float dap = sqrtf(sap), dan = sqrtf(san);
        float mg = M[lab[row] * CC + lab[hn]];
        float lo = fmaxf(dap - dan + mg, 0.0f);
        int bin = row & (NBIN - 1);
        atomicAdd(&bins[bin * BINSTRIDE], valid ? lo : 0.0f);
        atomicAdd(&bins[NBIN * BINSTRIDE + bin * BINSTRIDE], valid ? 1.0f : 0.0f);
    }
}

// ---------------- kernel 3: one wave folds the 64 bins + divides ----------------
__global__ __launch_bounds__(64) void k_div(const float* __restrict__ bins,
                                            float* __restrict__ out) {
    int t = threadIdx.x;
    float a = bins[t * BINSTRIDE];
    float b = bins[NBIN * BINSTRIDE + t * BINSTRIDE];
    #pragma unroll
    for (int m = 32; m; m >>= 1) {
        a += __shfl_xor(a, m);
        b += __shfl_xor(b, m);
    }
    if (t == 0) out[0] = a / fmaxf(b, 1.0f);
}

extern "C" void kernel_launch(void* const* d_in, const int* in_sizes, int n_in,
                              void* d_out, int out_size, void* d_ws, size_t ws_size,
                              hipStream_t stream) {
    const float* E   = (const float*)d_in[0];   // [B][D] fp32
    const float* M   = (const float*)d_in[1];   // [C][C] fp32
    const int*   lab = (const int*)d_in[2];     // [B]
    float* out = (float*)d_out;

    char* ws = (char*)d_ws;
    u16*   Ebf  = (u16*)ws;        ws += (size_t)BB * DD * 2;     // 2 MB
    float* sq   = (float*)ws;      ws += (size_t)BB * 4;
    u32*   gmax = (u32*)ws;        ws += (size_t)BB * 4;          // 32 KB
    u32*   gmin = (u32*)ws;        ws += (size_t)BB * 4;          // 32 KB
    float* bins = (float*)ws;      ws += (size_t)2 * NBIN * BINSTRIDE * 4; // 8 KB

    k_prep<<<BB / 4, 256, 0, stream>>>(E, sq, Ebf, gmax, gmin, bins);
    k_mine<<<dim3(BB / 256, NSLICE), 256, 0, stream>>>(Ebf, sq, lab, gmax, gmin);
    k_finalize<<<BB / 4, 256, 0, stream>>>(E, M, lab, gmax, gmin, bins);
    k_div<<<1, 64, 0, stream>>>(bins, out);
}